// Round 4
// baseline (487.708 us; speedup 1.0000x reference)
//
#include <hip/hip_runtime.h>
#include <hip/hip_bf16.h>
#include <math.h>

#define EMB 1024
#define DIM_FF 4096
#define HEADS 16
#define HD 64
#define TSEQ 2048
#define BATCH 4
#define MROWS (BATCH*TSEQ)
#define LN_EPS 1e-5f

typedef __attribute__((ext_vector_type(8))) short short8;
typedef __attribute__((ext_vector_type(4))) float f32x4;

#define MFMA16(a,b,c) __builtin_amdgcn_mfma_f32_16x16x32_bf16((a),(b),(c),0,0,0)

#define GLOBAL_AS(p) ((const __attribute__((address_space(1))) void*)(p))
#define LDS_AS(p)    ((__attribute__((address_space(3))) void*)(p))

__device__ __forceinline__ unsigned short bf16bits(float f){
    __hip_bfloat16 h = __float2bfloat16(f);
    unsigned short u;
    __builtin_memcpy(&u, &h, 2);
    return u;
}

// ---------------- convert fp32 -> bf16 (row-major) ----------------
__global__ __launch_bounds__(256)
void cvt_bf16(const float* __restrict__ in, __hip_bfloat16* __restrict__ out, int n4){
    int i = blockIdx.x*256 + threadIdx.x;
    if (i >= n4) return;
    f32x4 v = reinterpret_cast<const f32x4*>(in)[i];
    union { unsigned short us[4]; uint2 u2; } o;
    #pragma unroll
    for (int j=0;j<4;++j) o.us[j] = bf16bits(v[j]);
    *reinterpret_cast<uint2*>(reinterpret_cast<unsigned short*>(out) + (size_t)i*4) = o.u2;
}

// ---------------- transpose + convert: in (R x C) fp32 -> out (C x R) bf16 ----------------
__global__ __launch_bounds__(256)
void transpose_cvt(const float* __restrict__ in, __hip_bfloat16* __restrict__ out, int R, int C){
    __shared__ __hip_bfloat16 tile[32][33];
    int bx = blockIdx.x*32;  // col base
    int by = blockIdx.y*32;  // row base
    int x = bx + threadIdx.x;
    #pragma unroll
    for (int i = threadIdx.y; i < 32; i += 8){
        tile[i][threadIdx.x] = __float2bfloat16(in[(size_t)(by+i)*C + x]);
    }
    __syncthreads();
    int xo = by + threadIdx.x; // new col = old row
    #pragma unroll
    for (int i = threadIdx.y; i < 32; i += 8){
        out[(size_t)(bx+i)*R + xo] = tile[threadIdx.x][i];
    }
}

// ---------------- GEMM 128x128 (m97 structure) ----------------
// EPI: 1 = f32 out, 3 = +bias -> f32
template<int EPI>
__global__ __launch_bounds__(256, 2)
void gemm_bt(const __hip_bfloat16* __restrict__ A,
             const __hip_bfloat16* __restrict__ Bt,
             int M, int N, int K,
             float* __restrict__ Cf,
             const float* __restrict__ bias)
{
    __shared__ __align__(16) __hip_bfloat16 As[128*32];
    __shared__ __align__(16) __hip_bfloat16 Bs[128*32];
    const int tid = threadIdx.x;
    const int lane = tid & 63;
    const int wid = tid >> 6;
    const int wm = wid >> 1, wn = wid & 1;
    const int row0 = blockIdx.x * 128;
    const int col0 = blockIdx.y * 128;
    const int rA = lane & 15, kg = lane >> 4;

    const int lrow = lane >> 2;
    const int lcol = (lane & 3) << 3;

    f32x4 acc[4][4] = {};

    for (int kt = 0; kt < K; kt += 32) {
        __syncthreads();
        #pragma unroll
        for (int half = 0; half < 2; ++half) {
            const int rbase = (wid << 5) + (half << 4);
            const int r = rbase + lrow;
            __builtin_amdgcn_global_load_lds(
                GLOBAL_AS(A + (size_t)(row0 + r)*K + kt + lcol),
                LDS_AS(&As[rbase*32]), 16, 0, 0);
            __builtin_amdgcn_global_load_lds(
                GLOBAL_AS(Bt + (size_t)(col0 + r)*K + kt + lcol),
                LDS_AS(&Bs[rbase*32]), 16, 0, 0);
        }
        __syncthreads();
        short8 af[4], bfr[4];
        #pragma unroll
        for (int mi = 0; mi < 4; ++mi)
            af[mi] = *reinterpret_cast<const short8*>(&As[(wm*64 + mi*16 + rA)*32 + (kg<<3)]);
        #pragma unroll
        for (int ni = 0; ni < 4; ++ni)
            bfr[ni] = *reinterpret_cast<const short8*>(&Bs[(wn*64 + ni*16 + rA)*32 + (kg<<3)]);
        #pragma unroll
        for (int mi = 0; mi < 4; ++mi)
            #pragma unroll
            for (int ni = 0; ni < 4; ++ni)
                acc[mi][ni] = MFMA16(af[mi], bfr[ni], acc[mi][ni]);
    }

    #pragma unroll
    for (int mi=0; mi<4; ++mi) {
        #pragma unroll
        for (int ni=0; ni<4; ++ni) {
            #pragma unroll
            for (int j=0;j<4;++j){
                float v = acc[mi][ni][j];
                int grow = row0 + wm*64 + mi*16 + (kg<<2) + j;
                int gcol = col0 + wn*64 + ni*16 + rA;
                if constexpr (EPI==1) {
                    Cf[(size_t)grow*N + gcol] = v;
                } else {
                    Cf[(size_t)grow*N + gcol] = v + bias[gcol];
                }
            }
        }
    }
}

// ---------------- GEMM 256x256, BK=64, 8 waves, 4-phase/K-tile, counted vmcnt ----------------
// EPI: 0 = QKV scatter, 2 = +bias,relu -> bf16
#define GPHASE(P, STAGE_EXPR, WAIT_EXPR) do { \
    short8 af[2][2]; \
    _Pragma("unroll") \
    for (int i_=0;i_<2;++i_){ \
      _Pragma("unroll") \
      for (int kk_=0;kk_<2;++kk_) \
        af[i_][kk_] = *reinterpret_cast<const short8*>(pA + ((2*(P)+i_)*16+rA)*128 + (((kk_<<2)+kg)^swz)*16); \
    } \
    STAGE_EXPR; WAIT_EXPR; \
    __builtin_amdgcn_s_barrier(); \
    __builtin_amdgcn_s_setprio(1); \
    _Pragma("unroll") \
    for (int i_=0;i_<2;++i_){ \
      _Pragma("unroll") \
      for (int ni_=0;ni_<4;++ni_){ \
        acc[2*(P)+i_][ni_] = MFMA16(af[i_][0], bfr[ni_][0], acc[2*(P)+i_][ni_]); \
        acc[2*(P)+i_][ni_] = MFMA16(af[i_][1], bfr[ni_][1], acc[2*(P)+i_][ni_]); \
      } \
    } \
    __builtin_amdgcn_s_setprio(0); \
    __builtin_amdgcn_s_barrier(); \
} while(0)

template<int EPI>
__global__ __launch_bounds__(512, 2)
void gemm256(const __hip_bfloat16* __restrict__ A,
             const __hip_bfloat16* __restrict__ Bt,
             int M, int N, int K,
             __hip_bfloat16* __restrict__ Cb,
             const float* __restrict__ bias,
             __hip_bfloat16* __restrict__ qo,
             __hip_bfloat16* __restrict__ ko,
             __hip_bfloat16* __restrict__ vto)
{
    __shared__ __align__(16) __hip_bfloat16 Al[2][16384];
    __shared__ __align__(16) __hip_bfloat16 Bl[2][16384];
    const int tid = threadIdx.x;
    const int lane = tid & 63;
    const int wid = tid >> 6;
    const int wm = wid >> 2, wn = wid & 3;
    const int row0 = blockIdx.x * 256;
    const int col0 = blockIdx.y * 256;
    const int rA = lane & 15, kg = lane >> 4, swz = rA & 7;
    const int NT = K >> 6;

    // staging geometry: per half-tile (128 rows x 64 cols), 2 rounds; wave wid covers
    // rows [wid*8, wid*8+8) per round; lane l -> row +(l>>3), phys granule (l&7),
    // source logical granule (l&7)^(l>>3)  (pre-swizzled source, linear LDS dest)
    const int lr = lane >> 3;
    const int lg = (lane & 7) ^ lr;
    const __hip_bfloat16* sA = A  + (size_t)(row0 + wid*8 + lr)*K + lg*8;
    const __hip_bfloat16* sB = Bt + (size_t)(col0 + wid*8 + lr)*K + lg*8;
    char* dA = (char*)&Al[0][0] + wid*8*128;
    char* dB = (char*)&Bl[0][0] + wid*8*128;

    auto stage = [&](const __hip_bfloat16* s, char* d, int buf, int half, int kt){
        #pragma unroll
        for (int rr = 0; rr < 2; ++rr)
            __builtin_amdgcn_global_load_lds(
                GLOBAL_AS(s + (size_t)(half*128 + rr*64)*K + kt),
                LDS_AS(d + buf*32768 + (half*128 + rr*64)*128), 16, 0, 0);
    };

    f32x4 acc[8][4] = {};

    // prologue: tile0 (A0,A1,B0,B1) + tile1 (B0,B1); A(tile1) staged during tile0 p0/p1
    stage(sA, dA, 0, 0, 0); stage(sA, dA, 0, 1, 0);
    stage(sB, dB, 0, 0, 0); stage(sB, dB, 0, 1, 0);
    stage(sB, dB, 1, 0, 64); stage(sB, dB, 1, 1, 64);
    asm volatile("s_waitcnt vmcnt(4)" ::: "memory");
    __builtin_amdgcn_sched_barrier(0);
    __builtin_amdgcn_s_barrier();

    const char* cA = (const char*)&Al[0][0] + wm*128*128;
    const char* cB = (const char*)&Bl[0][0] + wn*64*128;

    for (int t = 0; t < NT; ++t) {
        const int buf = t & 1;
        const char* pA = cA + buf*32768;
        const char* pB = cB + buf*32768;
        // B fragments for this K-tile (read once, reused across 4 phases)
        short8 bfr[4][2];
        #pragma unroll
        for (int ni = 0; ni < 4; ++ni)
            #pragma unroll
            for (int kk = 0; kk < 2; ++kk)
                bfr[ni][kk] = *reinterpret_cast<const short8*>(pB + (ni*16+rA)*128 + (((kk<<2)+kg)^swz)*16);

        GPHASE(0, if (t+1 < NT) stage(sA, dA, buf^1, 0, (t+1)*64), );
        GPHASE(1, if (t+1 < NT) stage(sA, dA, buf^1, 1, (t+1)*64), );
        GPHASE(2, if (t+2 < NT) stage(sB, dB, buf,   0, (t+2)*64), );
        GPHASE(3, if (t+2 < NT) stage(sB, dB, buf,   1, (t+2)*64),
            if (t+2 < NT) { asm volatile("s_waitcnt vmcnt(4)" ::: "memory"); }
            else          { asm volatile("s_waitcnt vmcnt(0)" ::: "memory"); }
            __builtin_amdgcn_sched_barrier(0) );
    }

    #pragma unroll
    for (int mi=0; mi<8; ++mi) {
        #pragma unroll
        for (int ni=0; ni<4; ++ni) {
            #pragma unroll
            for (int j=0;j<4;++j){
                float v = acc[mi][ni][j];
                int grow = row0 + wm*128 + mi*16 + (kg<<2) + j;
                int gcol = col0 + wn*64 + ni*16 + rA;
                if constexpr (EPI==0) {
                    int b = grow >> 11, t = grow & 2047;
                    int which = gcol >> 10, hdx = gcol & 1023;
                    int h = hdx >> 6, d = hdx & 63;
                    int bh = b*HEADS + h;
                    __hip_bfloat16 bv = __float2bfloat16(v);
                    if (which==0)      qo[((size_t)bh*TSEQ + t)*HD + d] = bv;
                    else if (which==1) ko[((size_t)bh*TSEQ + t)*HD + d] = bv;
                    else               vto[((size_t)bh*HD + d)*TSEQ + t] = bv;
                } else {
                    v += bias[gcol]; v = v > 0.0f ? v : 0.0f;
                    Cb[(size_t)grow*N + gcol] = __float2bfloat16(v);
                }
            }
        }
    }
}

// ---------------- flash attention ----------------
// Swapped QK^T + lane-local softmax; K/V staged to LDS (double-buffered) via
// global_load_lds with pre-swizzled SOURCE; 1 barrier per KV tile.
__global__ __launch_bounds__(256, 4)
void attn_fwd(const __hip_bfloat16* __restrict__ q,
              const __hip_bfloat16* __restrict__ k,
              const __hip_bfloat16* __restrict__ vt,
              __hip_bfloat16* __restrict__ merged)
{
    const int wg = (blockIdx.x & 7) * 256 + (blockIdx.x >> 3);
    const int bh = wg >> 5;
    const int qt = wg & 31;
    const int wid = threadIdx.x >> 6, lane = threadIdx.x & 63;
    const int rA = lane & 15, kg = lane >> 4;
    const int qrow0 = qt*64 + wid*16;
    const __hip_bfloat16* Qh = q  + (size_t)bh*TSEQ*HD;
    const __hip_bfloat16* Kh = k  + (size_t)bh*TSEQ*HD;
    const __hip_bfloat16* Vh = vt + (size_t)bh*HD*TSEQ;

    __shared__ __align__(16) __hip_bfloat16 Kl[2][64*64];
    __shared__ __align__(16) __hip_bfloat16 Vl[2][64*64];
    __shared__ __align__(16) __hip_bfloat16 plds[4][8][16][8];

    short8 aQ0 = *reinterpret_cast<const short8*>(Qh + (size_t)(qrow0+rA)*HD + (kg<<3));
    short8 aQ1 = *reinterpret_cast<const short8*>(Qh + (size_t)(qrow0+rA)*HD + 32 + (kg<<3));

    const int lrow = lane >> 3;
    const int lslot = ((lane & 7) ^ lrow) << 3;
    const __hip_bfloat16* sK0 = Kh + (size_t)(wid*16 + lrow)*HD + lslot;
    const __hip_bfloat16* sV0 = Vh + (size_t)(wid*16 + lrow)*TSEQ + lslot;
    const int dOff = wid*16*64;

    f32x4 O[4] = {};
    float m = -1e30f, l = 0.f;
    const int swz = rA & 7;

    {
        __builtin_amdgcn_global_load_lds(GLOBAL_AS(sK0),          LDS_AS(&Kl[0][dOff]),        16, 0, 0);
        __builtin_amdgcn_global_load_lds(GLOBAL_AS(sK0 + 8*HD),   LDS_AS(&Kl[0][dOff + 8*64]), 16, 0, 0);
        __builtin_amdgcn_global_load_lds(GLOBAL_AS(sV0),          LDS_AS(&Vl[0][dOff]),        16, 0, 0);
        __builtin_amdgcn_global_load_lds(GLOBAL_AS(sV0 + 8*TSEQ), LDS_AS(&Vl[0][dOff + 8*64]), 16, 0, 0);
    }
    __syncthreads();

    for (int t = 0; t < TSEQ/64; ++t) {
        const int b = t & 1;
        if (t < TSEQ/64 - 1) {
            const int kt = (t+1)*64;
            __builtin_amdgcn_global_load_lds(GLOBAL_AS(sK0 + (size_t)kt*HD),          LDS_AS(&Kl[b^1][dOff]),        16, 0, 0);
            __builtin_amdgcn_global_load_lds(GLOBAL_AS(sK0 + (size_t)(kt+8)*HD),      LDS_AS(&Kl[b^1][dOff + 8*64]), 16, 0, 0);
            __builtin_amdgcn_global_load_lds(GLOBAL_AS(sV0 + kt),                     LDS_AS(&Vl[b^1][dOff]),        16, 0, 0);
            __builtin_amdgcn_global_load_lds(GLOBAL_AS(sV0 + 8*TSEQ + kt),            LDS_AS(&Vl[b^1][dOff + 8*64]), 16, 0, 0);
        }
        const char* Kb = (const char*)&Kl[b][0];
        const char* Vb = (const char*)&Vl[b][0];

        f32x4 st[4];
        #pragma unroll
        for (int kb = 0; kb < 4; ++kb) {
            const int ro = (kb*16 + rA) * 128;
            short8 aK0 = *reinterpret_cast<const short8*>(Kb + ro + ((kg ^ swz) << 4));
            short8 aK1 = *reinterpret_cast<const short8*>(Kb + ro + (((4+kg) ^ swz) << 4));
            f32x4 z = {};
            z = MFMA16(aK0, aQ0, z);
            st[kb] = MFMA16(aK1, aQ1, z);
        }
        f32x4 sm01, sm;
        #pragma unroll
        for (int j=0;j<4;++j) sm01[j] = fmaxf(st[0][j], st[1][j]);
        #pragma unroll
        for (int j=0;j<4;++j) sm[j] = fmaxf(sm01[j], fmaxf(st[2][j], st[3][j]));
        float mx = fmaxf(fmaxf(sm[0], sm[1]), fmaxf(sm[2], sm[3]));
        mx = fmaxf(mx, __shfl_xor(mx, 16));
        mx = fmaxf(mx, __shfl_xor(mx, 32));
        float mn = fmaxf(m, mx*0.125f);
        float al = __expf(m - mn);
        f32x4 ps[4];
        #pragma unroll
        for (int kb=0; kb<4; ++kb)
            #pragma unroll
            for (int j=0;j<4;++j)
                ps[kb][j] = __expf(fmaf(st[kb][j], 0.125f, -mn));
        f32x4 ssv = (ps[0]+ps[1]) + (ps[2]+ps[3]);
        float rs = (ssv[0]+ssv[1]) + (ssv[2]+ssv[3]);
        rs += __shfl_xor(rs, 16);
        rs += __shfl_xor(rs, 32);
        l = l*al + rs; m = mn;
        float alq[4];
        #pragma unroll
        for (int j=0;j<4;++j) alq[j] = __shfl(al, (kg<<2)+j);
        #pragma unroll
        for (int dt=0; dt<4; ++dt)
            #pragma unroll
            for (int j=0;j<4;++j) O[dt][j] *= alq[j];
        #pragma unroll
        for (int kb=0; kb<4; ++kb) {
            uint2 w;
            w.x = (unsigned)bf16bits(ps[kb][0]) | ((unsigned)bf16bits(ps[kb][1]) << 16);
            w.y = (unsigned)bf16bits(ps[kb][2]) | ((unsigned)bf16bits(ps[kb][3]) << 16);
            *reinterpret_cast<uint2*>(&plds[wid][2*kb + (kg>>1)][rA][(kg&1)<<2]) = w;
        }
        short8 aP0 = *reinterpret_cast<const short8*>(&plds[wid][kg][rA][0]);
        short8 aP1 = *reinterpret_cast<const short8*>(&plds[wid][4+kg][rA][0]);
        #pragma unroll
        for (int dt=0; dt<4; ++dt) {
            const int vo = (dt*16 + rA) * 128;
            short8 bV0 = *reinterpret_cast<const short8*>(Vb + vo + ((kg ^ swz) << 4));
            short8 bV1 = *reinterpret_cast<const short8*>(Vb + vo + (((4+kg) ^ swz) << 4));
            O[dt] = MFMA16(aP0, bV0, O[dt]);
            O[dt] = MFMA16(aP1, bV1, O[dt]);
        }
        __syncthreads();
    }

    float lq[4];
    #pragma unroll
    for (int j=0;j<4;++j) lq[j] = 1.0f / __shfl(l, (kg<<2)+j);
    const int b = bh >> 4, h = bh & 15;
    #pragma unroll
    for (int dt=0; dt<4; ++dt){
        #pragma unroll
        for (int j=0;j<4;++j){
            int t = qrow0 + (kg<<2) + j;
            int col = h*HD + dt*16 + rA;
            merged[((size_t)(b*TSEQ + t))*EMB + col] = __float2bfloat16(O[dt][j]*lq[j]);
        }
    }
}

// ---------------- residual + layer norm ----------------
__global__ __launch_bounds__(256)
void ln_res(const float* __restrict__ a, const float* __restrict__ res,
            const float* __restrict__ gain, const float* __restrict__ bias,
            float* __restrict__ outf, __hip_bfloat16* __restrict__ outb)
{
    const int row = blockIdx.x;
    const int tid = threadIdx.x;
    const int lane = tid & 63, wid = tid >> 6;
    const size_t base = (size_t)row * EMB;
    f32x4 va = *reinterpret_cast<const f32x4*>(a + base + tid*4);
    f32x4 vr = *reinterpret_cast<const f32x4*>(res + base + tid*4);
    f32x4 v = va + vr;
    float s = v[0]+v[1]+v[2]+v[3];
    #pragma unroll
    for (int off=1; off<64; off<<=1) s += __shfl_xor(s, off);
    __shared__ float red1[4], red2[4];
    if (lane==0) red1[wid] = s;
    __syncthreads();
    float mean = (red1[0]+red1[1]+red1[2]+red1[3]) * (1.0f/EMB);
    f32x4 d;
    #pragma unroll
    for (int j=0;j<4;++j) d[j] = v[j] - mean;
    float qs = d[0]*d[0]+d[1]*d[1]+d[2]*d[2]+d[3]*d[3];
    #pragma unroll
    for (int off=1; off<64; off<<=1) qs += __shfl_xor(qs, off);
    if (lane==0) red2[wid] = qs;
    __syncthreads();
    float var = (red2[0]+red2[1]+red2[2]+red2[3]) * (1.0f/EMB);
    float r = 1.0f/(sqrtf(var)+LN_EPS);
    f32x4 g = *reinterpret_cast<const f32x4*>(gain + tid*4);
    f32x4 bb = *reinterpret_cast<const f32x4*>(bias + tid*4);
    f32x4 o;
    #pragma unroll
    for (int j=0;j<4;++j) o[j] = g[j]*(d[j]*r) + bb[j];
    *reinterpret_cast<f32x4*>(outf + base + tid*4) = o;
    if (outb) {
        union { unsigned short us[4]; uint2 u2; } ob;
        #pragma unroll
        for (int j=0;j<4;++j) ob.us[j] = bf16bits(o[j]);
        *reinterpret_cast<uint2*>(reinterpret_cast<unsigned short*>(outb) + base + tid*4) = ob.u2;
    }
}

// ---------------- launch ----------------
extern "C" void kernel_launch(void* const* d_in, const int* in_sizes, int n_in,
                              void* d_out, int out_size, void* d_ws, size_t ws_size,
                              hipStream_t stream) {
    const float* x   = (const float*)d_in[0];
    const float* Wq  = (const float*)d_in[1];
    const float* Wk  = (const float*)d_in[2];
    const float* Wv  = (const float*)d_in[3];
    const float* Wo  = (const float*)d_in[4];
    const float* W1  = (const float*)d_in[5];
    const float* b1  = (const float*)d_in[6];
    const float* W2  = (const float*)d_in[7];
    const float* b2  = (const float*)d_in[8];
    const float* gain1 = (const float*)d_in[9];
    const float* bias1 = (const float*)d_in[10];
    const float* gain2 = (const float*)d_in[11];
    const float* bias2 = (const float*)d_in[12];

    char* ws = (char*)d_ws;
    __hip_bfloat16* Wqkv_t = (__hip_bfloat16*)(ws + 0);          // 3072x1024
    __hip_bfloat16* Wo_t   = (__hip_bfloat16*)(ws + 6291456);    // 1024x1024
    __hip_bfloat16* W1_t   = (__hip_bfloat16*)(ws + 8388608);    // 4096x1024
    __hip_bfloat16* W2_t   = (__hip_bfloat16*)(ws + 16777216);   // 1024x4096
    __hip_bfloat16* xb     = (__hip_bfloat16*)(ws + 25165824);   // 8192x1024
    __hip_bfloat16* qb     = (__hip_bfloat16*)(ws + 41943040);   // 64x2048x64
    __hip_bfloat16* kb     = (__hip_bfloat16*)(ws + 58720256);
    __hip_bfloat16* vtb    = (__hip_bfloat16*)(ws + 75497472);   // 64x64x2048
    __hip_bfloat16* h1     = (__hip_bfloat16*)(ws + 25165824);   // reuse xb..vt, 8192x4096
    __hip_bfloat16* mergedb= (__hip_bfloat16*)(ws + 92274688);   // 8192x1024
    float*          attended=(float*)(ws + 109051904);           // 8192x1024 f32
    float*          ff     = (float*)(ws + 92274688);            // reuse merged+attended
    float*          x1f    = (float*)(ws + 142606336);           // 8192x1024 f32
    __hip_bfloat16* x1b    = (__hip_bfloat16*)(ws + 176160768);  // 8192x1024
    float*          outf   = (float*)d_out;

    dim3 tb(32,8);
    transpose_cvt<<<dim3(32,32),  tb, 0, stream>>>(Wq, Wqkv_t,                 1024, 1024);
    transpose_cvt<<<dim3(32,32),  tb, 0, stream>>>(Wk, Wqkv_t + 1024*1024,     1024, 1024);
    transpose_cvt<<<dim3(32,32),  tb, 0, stream>>>(Wv, Wqkv_t + 2*1024*1024,   1024, 1024);
    transpose_cvt<<<dim3(32,32),  tb, 0, stream>>>(Wo, Wo_t,                   1024, 1024);
    transpose_cvt<<<dim3(128,32), tb, 0, stream>>>(W1, W1_t,                   1024, 4096);
    transpose_cvt<<<dim3(32,128), tb, 0, stream>>>(W2, W2_t,                   4096, 1024);
    cvt_bf16<<<(MROWS*EMB/4 + 255)/256, 256, 0, stream>>>(x, xb, MROWS*EMB/4);

    // QKV projection (fused, 256^2 8-phase)
    gemm256<0><<<dim3(MROWS/256, 3072/256), 512, 0, stream>>>(
        xb, Wqkv_t, MROWS, 3072, EMB, nullptr, nullptr, qb, kb, vtb);
    // attention
    attn_fwd<<<dim3(2048), 256, 0, stream>>>(qb, kb, vtb, mergedb);
    // output projection (128^2)
    gemm_bt<1><<<dim3(MROWS/128, EMB/128), 256, 0, stream>>>(
        mergedb, Wo_t, MROWS, EMB, EMB, attended, nullptr);
    // residual + LN1
    ln_res<<<MROWS, 256, 0, stream>>>(attended, x, gain1, bias1, x1f, x1b);
    // FF1: relu(x1 @ W1 + b1) -> bf16 (256^2 8-phase)
    gemm256<2><<<dim3(MROWS/256, DIM_FF/256), 512, 0, stream>>>(
        x1b, W1_t, MROWS, DIM_FF, EMB, h1, b1, nullptr, nullptr, nullptr);
    // FF2: h1 @ W2 + b2 -> f32 (128^2)
    gemm_bt<3><<<dim3(MROWS/128, EMB/128), 256, 0, stream>>>(
        h1, W2_t, MROWS, EMB, DIM_FF, ff, b2);
    // residual + LN2 -> out
    ln_res<<<MROWS, 256, 0, stream>>>(ff, x1f, gain2, bias2, outf, nullptr);
}

// Round 5
// 442.574 us; speedup vs baseline: 1.1020x; 1.1020x over previous
//
#include <hip/hip_runtime.h>
#include <hip/hip_bf16.h>
#include <math.h>

#define EMB 1024
#define DIM_FF 4096
#define HEADS 16
#define HD 64
#define TSEQ 2048
#define BATCH 4
#define MROWS (BATCH*TSEQ)
#define LN_EPS 1e-5f

typedef __attribute__((ext_vector_type(8))) short short8;
typedef __attribute__((ext_vector_type(4))) float f32x4;

#define MFMA16(a,b,c) __builtin_amdgcn_mfma_f32_16x16x32_bf16((a),(b),(c),0,0,0)

#define GLOBAL_AS(p) ((const __attribute__((address_space(1))) void*)(p))
#define LDS_AS(p)    ((__attribute__((address_space(3))) void*)(p))

__device__ __forceinline__ unsigned short bf16bits(float f){
    __hip_bfloat16 h = __float2bfloat16(f);
    unsigned short u;
    __builtin_memcpy(&u, &h, 2);
    return u;
}
__device__ __forceinline__ unsigned cvtpk_bf16(float lo, float hi){
    unsigned r;
    asm("v_cvt_pk_bf16_f32 %0, %1, %2" : "=v"(r) : "v"(lo), "v"(hi));
    return r;
}
__device__ __forceinline__ f32x4 ld4bf(const __hip_bfloat16* p){
    ushort4 u = *reinterpret_cast<const ushort4*>(p);
    union{unsigned i; float f;} c0,c1,c2,c3;
    c0.i=(unsigned)u.x<<16; c1.i=(unsigned)u.y<<16; c2.i=(unsigned)u.z<<16; c3.i=(unsigned)u.w<<16;
    f32x4 r; r[0]=c0.f; r[1]=c1.f; r[2]=c2.f; r[3]=c3.f;
    return r;
}

// ---------------- convert fp32 -> bf16 (row-major) ----------------
__global__ __launch_bounds__(256)
void cvt_bf16(const float* __restrict__ in, __hip_bfloat16* __restrict__ out, int n4){
    int i = blockIdx.x*256 + threadIdx.x;
    if (i >= n4) return;
    f32x4 v = reinterpret_cast<const f32x4*>(in)[i];
    uint2 o;
    o.x = cvtpk_bf16(v[0], v[1]);
    o.y = cvtpk_bf16(v[2], v[3]);
    *reinterpret_cast<uint2*>(reinterpret_cast<unsigned short*>(out) + (size_t)i*4) = o;
}

// ---------------- fused transpose of the four 1024x1024 weights ----------------
__global__ __launch_bounds__(256)
void transpose_cvt4(const float* __restrict__ s0, const float* __restrict__ s1,
                    const float* __restrict__ s2, const float* __restrict__ s3,
                    __hip_bfloat16* __restrict__ out){
    const float* in = blockIdx.z==0 ? s0 : blockIdx.z==1 ? s1 : blockIdx.z==2 ? s2 : s3;
    __hip_bfloat16* dst = out + (size_t)blockIdx.z*1024*1024;
    __shared__ __hip_bfloat16 tile[32][33];
    int bx = blockIdx.x*32, by = blockIdx.y*32;
    int x = bx + threadIdx.x;
    #pragma unroll
    for (int i = threadIdx.y; i < 32; i += 8)
        tile[i][threadIdx.x] = __float2bfloat16(in[(size_t)(by+i)*1024 + x]);
    __syncthreads();
    int xo = by + threadIdx.x;
    #pragma unroll
    for (int i = threadIdx.y; i < 32; i += 8)
        dst[(size_t)(bx+i)*1024 + xo] = tile[threadIdx.x][i];
}

// ---------------- transpose + convert: in (R x C) fp32 -> out (C x R) bf16 ----------------
__global__ __launch_bounds__(256)
void transpose_cvt(const float* __restrict__ in, __hip_bfloat16* __restrict__ out, int R, int C){
    __shared__ __hip_bfloat16 tile[32][33];
    int bx = blockIdx.x*32, by = blockIdx.y*32;
    int x = bx + threadIdx.x;
    #pragma unroll
    for (int i = threadIdx.y; i < 32; i += 8)
        tile[i][threadIdx.x] = __float2bfloat16(in[(size_t)(by+i)*C + x]);
    __syncthreads();
    int xo = by + threadIdx.x;
    #pragma unroll
    for (int i = threadIdx.y; i < 32; i += 8)
        out[(size_t)(bx+i)*R + xo] = tile[threadIdx.x][i];
}

// ---------------- GEMM 128x128 (m97 structure) ----------------
// EPI: 1 = bf16 out, 3 = +bias -> bf16
template<int EPI>
__global__ __launch_bounds__(256, 2)
void gemm_bt(const __hip_bfloat16* __restrict__ A,
             const __hip_bfloat16* __restrict__ Bt,
             int M, int N, int K,
             __hip_bfloat16* __restrict__ Cb,
             const float* __restrict__ bias)
{
    __shared__ __align__(16) __hip_bfloat16 As[128*32];
    __shared__ __align__(16) __hip_bfloat16 Bs[128*32];
    const int tid = threadIdx.x;
    const int lane = tid & 63;
    const int wid = tid >> 6;
    const int wm = wid >> 1, wn = wid & 1;
    const int row0 = blockIdx.x * 128;
    const int col0 = blockIdx.y * 128;
    const int rA = lane & 15, kg = lane >> 4;

    const int lrow = lane >> 2;
    const int lcol = (lane & 3) << 3;

    f32x4 acc[4][4] = {};

    for (int kt = 0; kt < K; kt += 32) {
        __syncthreads();
        #pragma unroll
        for (int half = 0; half < 2; ++half) {
            const int rbase = (wid << 5) + (half << 4);
            const int r = rbase + lrow;
            __builtin_amdgcn_global_load_lds(
                GLOBAL_AS(A + (size_t)(row0 + r)*K + kt + lcol),
                LDS_AS(&As[rbase*32]), 16, 0, 0);
            __builtin_amdgcn_global_load_lds(
                GLOBAL_AS(Bt + (size_t)(col0 + r)*K + kt + lcol),
                LDS_AS(&Bs[rbase*32]), 16, 0, 0);
        }
        __syncthreads();
        short8 af[4], bfr[4];
        #pragma unroll
        for (int mi = 0; mi < 4; ++mi)
            af[mi] = *reinterpret_cast<const short8*>(&As[(wm*64 + mi*16 + rA)*32 + (kg<<3)]);
        #pragma unroll
        for (int ni = 0; ni < 4; ++ni)
            bfr[ni] = *reinterpret_cast<const short8*>(&Bs[(wn*64 + ni*16 + rA)*32 + (kg<<3)]);
        #pragma unroll
        for (int mi = 0; mi < 4; ++mi)
            #pragma unroll
            for (int ni = 0; ni < 4; ++ni)
                acc[mi][ni] = MFMA16(af[mi], bfr[ni], acc[mi][ni]);
    }

    #pragma unroll
    for (int mi=0; mi<4; ++mi) {
        #pragma unroll
        for (int ni=0; ni<4; ++ni) {
            #pragma unroll
            for (int j=0;j<4;++j){
                float v = acc[mi][ni][j];
                int grow = row0 + wm*64 + mi*16 + (kg<<2) + j;
                int gcol = col0 + wn*64 + ni*16 + rA;
                if constexpr (EPI==3) v += bias[gcol];
                Cb[(size_t)grow*N + gcol] = __float2bfloat16(v);
            }
        }
    }
}

// ---------------- GEMM 256x256, BK=64, 8 waves, 4-phase/K-tile, counted vmcnt ----------------
// EPI: 0 = QKV scatter (Q pre-scaled by 0.125), 2 = +bias,relu -> bf16
#define GPHASE(P, STAGE_EXPR, WAIT_EXPR) do { \
    short8 af[2][2]; \
    _Pragma("unroll") \
    for (int i_=0;i_<2;++i_){ \
      _Pragma("unroll") \
      for (int kk_=0;kk_<2;++kk_) \
        af[i_][kk_] = *reinterpret_cast<const short8*>(pA + ((2*(P)+i_)*16+rA)*128 + (((kk_<<2)+kg)^swz)*16); \
    } \
    STAGE_EXPR; WAIT_EXPR; \
    __builtin_amdgcn_s_barrier(); \
    __builtin_amdgcn_s_setprio(1); \
    _Pragma("unroll") \
    for (int i_=0;i_<2;++i_){ \
      _Pragma("unroll") \
      for (int ni_=0;ni_<4;++ni_){ \
        acc[2*(P)+i_][ni_] = MFMA16(af[i_][0], bfr[ni_][0], acc[2*(P)+i_][ni_]); \
        acc[2*(P)+i_][ni_] = MFMA16(af[i_][1], bfr[ni_][1], acc[2*(P)+i_][ni_]); \
      } \
    } \
    __builtin_amdgcn_s_setprio(0); \
    __builtin_amdgcn_s_barrier(); \
} while(0)

template<int EPI>
__global__ __launch_bounds__(512, 2)
void gemm256(const __hip_bfloat16* __restrict__ A,
             const __hip_bfloat16* __restrict__ Bt,
             int M, int N, int K,
             __hip_bfloat16* __restrict__ Cb,
             const float* __restrict__ bias,
             __hip_bfloat16* __restrict__ qo,
             __hip_bfloat16* __restrict__ ko,
             __hip_bfloat16* __restrict__ vto)
{
    __shared__ __align__(16) __hip_bfloat16 Al[2][16384];
    __shared__ __align__(16) __hip_bfloat16 Bl[2][16384];
    const int tid = threadIdx.x;
    const int lane = tid & 63;
    const int wid = tid >> 6;
    const int wm = wid >> 2, wn = wid & 3;
    const int row0 = blockIdx.x * 256;
    const int col0 = blockIdx.y * 256;
    const int rA = lane & 15, kg = lane >> 4, swz = rA & 7;
    const int NT = K >> 6;

    const int lr = lane >> 3;
    const int lg = (lane & 7) ^ lr;
    const __hip_bfloat16* sA = A  + (size_t)(row0 + wid*8 + lr)*K + lg*8;
    const __hip_bfloat16* sB = Bt + (size_t)(col0 + wid*8 + lr)*K + lg*8;
    char* dA = (char*)&Al[0][0] + wid*8*128;
    char* dB = (char*)&Bl[0][0] + wid*8*128;

    auto stage = [&](const __hip_bfloat16* s, char* d, int buf, int half, int kt){
        #pragma unroll
        for (int rr = 0; rr < 2; ++rr)
            __builtin_amdgcn_global_load_lds(
                GLOBAL_AS(s + (size_t)(half*128 + rr*64)*K + kt),
                LDS_AS(d + buf*32768 + (half*128 + rr*64)*128), 16, 0, 0);
    };

    f32x4 acc[8][4] = {};

    stage(sA, dA, 0, 0, 0); stage(sA, dA, 0, 1, 0);
    stage(sB, dB, 0, 0, 0); stage(sB, dB, 0, 1, 0);
    stage(sB, dB, 1, 0, 64); stage(sB, dB, 1, 1, 64);
    asm volatile("s_waitcnt vmcnt(4)" ::: "memory");
    __builtin_amdgcn_sched_barrier(0);
    __builtin_amdgcn_s_barrier();

    const char* cA = (const char*)&Al[0][0] + wm*128*128;
    const char* cB = (const char*)&Bl[0][0] + wn*64*128;

    for (int t = 0; t < NT; ++t) {
        const int buf = t & 1;
        const char* pA = cA + buf*32768;
        const char* pB = cB + buf*32768;
        short8 bfr[4][2];
        #pragma unroll
        for (int ni = 0; ni < 4; ++ni)
            #pragma unroll
            for (int kk = 0; kk < 2; ++kk)
                bfr[ni][kk] = *reinterpret_cast<const short8*>(pB + (ni*16+rA)*128 + (((kk<<2)+kg)^swz)*16);

        GPHASE(0, if (t+1 < NT) stage(sA, dA, buf^1, 0, (t+1)*64), );
        GPHASE(1, if (t+1 < NT) stage(sA, dA, buf^1, 1, (t+1)*64), );
        GPHASE(2, if (t+2 < NT) stage(sB, dB, buf,   0, (t+2)*64), );
        GPHASE(3, if (t+2 < NT) stage(sB, dB, buf,   1, (t+2)*64),
            if (t+2 < NT) { asm volatile("s_waitcnt vmcnt(4)" ::: "memory"); }
            else          { asm volatile("s_waitcnt vmcnt(0)" ::: "memory"); }
            __builtin_amdgcn_sched_barrier(0) );
    }

    #pragma unroll
    for (int mi=0; mi<8; ++mi) {
        #pragma unroll
        for (int ni=0; ni<4; ++ni) {
            #pragma unroll
            for (int j=0;j<4;++j){
                float v = acc[mi][ni][j];
                int grow = row0 + wm*128 + mi*16 + (kg<<2) + j;
                int gcol = col0 + wn*64 + ni*16 + rA;
                if constexpr (EPI==0) {
                    int b = grow >> 11, t = grow & 2047;
                    int which = gcol >> 10, hdx = gcol & 1023;
                    int h = hdx >> 6, d = hdx & 63;
                    int bh = b*HEADS + h;
                    if (which==0)      qo[((size_t)bh*TSEQ + t)*HD + d] = __float2bfloat16(v*0.125f);
                    else if (which==1) ko[((size_t)bh*TSEQ + t)*HD + d] = __float2bfloat16(v);
                    else               vto[((size_t)bh*HD + d)*TSEQ + t] = __float2bfloat16(v);
                } else {
                    v += bias[gcol]; v = v > 0.0f ? v : 0.0f;
                    Cb[(size_t)grow*N + gcol] = __float2bfloat16(v);
                }
            }
        }
    }
}

// ---------------- flash attention ----------------
// Swapped QK^T + lane-local softmax; K/V staged to LDS (double-buffered) via
// global_load_lds with pre-swizzled SOURCE; defer-max (THR=8); cvt_pk packing;
// per-lane l partial reduced once at the end. Q comes in pre-scaled by 1/8.
__global__ __launch_bounds__(256, 4)
void attn_fwd(const __hip_bfloat16* __restrict__ q,
              const __hip_bfloat16* __restrict__ k,
              const __hip_bfloat16* __restrict__ vt,
              __hip_bfloat16* __restrict__ merged)
{
    const int wg = (blockIdx.x & 7) * 256 + (blockIdx.x >> 3);
    const int bh = wg >> 5;
    const int qt = wg & 31;
    const int wid = threadIdx.x >> 6, lane = threadIdx.x & 63;
    const int rA = lane & 15, kg = lane >> 4;
    const int qrow0 = qt*64 + wid*16;
    const __hip_bfloat16* Qh = q  + (size_t)bh*TSEQ*HD;
    const __hip_bfloat16* Kh = k  + (size_t)bh*TSEQ*HD;
    const __hip_bfloat16* Vh = vt + (size_t)bh*HD*TSEQ;

    __shared__ __align__(16) __hip_bfloat16 Kl[2][64*64];
    __shared__ __align__(16) __hip_bfloat16 Vl[2][64*64];
    __shared__ __align__(16) __hip_bfloat16 plds[4][8][16][8];

    short8 aQ0 = *reinterpret_cast<const short8*>(Qh + (size_t)(qrow0+rA)*HD + (kg<<3));
    short8 aQ1 = *reinterpret_cast<const short8*>(Qh + (size_t)(qrow0+rA)*HD + 32 + (kg<<3));

    const int lrow = lane >> 3;
    const int lslot = ((lane & 7) ^ lrow) << 3;
    const __hip_bfloat16* sK0 = Kh + (size_t)(wid*16 + lrow)*HD + lslot;
    const __hip_bfloat16* sV0 = Vh + (size_t)(wid*16 + lrow)*TSEQ + lslot;
    const int dOff = wid*16*64;

    f32x4 O[4] = {};
    float m = -1e30f, lpart = 0.f;
    const int swz = rA & 7;

    {
        __builtin_amdgcn_global_load_lds(GLOBAL_AS(sK0),          LDS_AS(&Kl[0][dOff]),        16, 0, 0);
        __builtin_amdgcn_global_load_lds(GLOBAL_AS(sK0 + 8*HD),   LDS_AS(&Kl[0][dOff + 8*64]), 16, 0, 0);
        __builtin_amdgcn_global_load_lds(GLOBAL_AS(sV0),          LDS_AS(&Vl[0][dOff]),        16, 0, 0);
        __builtin_amdgcn_global_load_lds(GLOBAL_AS(sV0 + 8*TSEQ), LDS_AS(&Vl[0][dOff + 8*64]), 16, 0, 0);
    }
    __syncthreads();

    for (int t = 0; t < TSEQ/64; ++t) {
        const int b = t & 1;
        if (t < TSEQ/64 - 1) {
            const int kt = (t+1)*64;
            __builtin_amdgcn_global_load_lds(GLOBAL_AS(sK0 + (size_t)kt*HD),     LDS_AS(&Kl[b^1][dOff]),        16, 0, 0);
            __builtin_amdgcn_global_load_lds(GLOBAL_AS(sK0 + (size_t)(kt+8)*HD), LDS_AS(&Kl[b^1][dOff + 8*64]), 16, 0, 0);
            __builtin_amdgcn_global_load_lds(GLOBAL_AS(sV0 + kt),                LDS_AS(&Vl[b^1][dOff]),        16, 0, 0);
            __builtin_amdgcn_global_load_lds(GLOBAL_AS(sV0 + 8*TSEQ + kt),       LDS_AS(&Vl[b^1][dOff + 8*64]), 16, 0, 0);
        }
        const char* Kb = (const char*)&Kl[b][0];
        const char* Vb = (const char*)&Vl[b][0];

        f32x4 st[4];
        #pragma unroll
        for (int kb = 0; kb < 4; ++kb) {
            const int ro = (kb*16 + rA) * 128;
            short8 aK0 = *reinterpret_cast<const short8*>(Kb + ro + ((kg ^ swz) << 4));
            short8 aK1 = *reinterpret_cast<const short8*>(Kb + ro + (((4+kg) ^ swz) << 4));
            f32x4 z = {};
            z = MFMA16(aK0, aQ0, z);
            st[kb] = MFMA16(aK1, aQ1, z);
        }
        // tile max of this lane's q-row
        f32x4 m4 = st[0];
        #pragma unroll
        for (int kb=1; kb<4; ++kb)
            #pragma unroll
            for (int j=0;j<4;++j) m4[j] = fmaxf(m4[j], st[kb][j]);
        float mx = fmaxf(fmaxf(m4[0], m4[1]), fmaxf(m4[2], m4[3]));
        mx = fmaxf(mx, __shfl_xor(mx, 16));
        mx = fmaxf(mx, __shfl_xor(mx, 32));
        // defer-max: only rescale when some row grew by > 8
        if (!__all(mx - m <= 8.0f)) {
            float mn = fmaxf(m, mx);
            float al = __expf(m - mn);
            lpart *= al;
            float alq[4];
            #pragma unroll
            for (int j=0;j<4;++j) alq[j] = __shfl(al, (kg<<2)+j);
            #pragma unroll
            for (int dt=0; dt<4; ++dt)
                #pragma unroll
                for (int j=0;j<4;++j) O[dt][j] *= alq[j];
            m = mn;
        }
        f32x4 ps[4];
        #pragma unroll
        for (int kb=0; kb<4; ++kb)
            #pragma unroll
            for (int j=0;j<4;++j)
                ps[kb][j] = __expf(st[kb][j] - m);
        f32x4 ssv = (ps[0]+ps[1]) + (ps[2]+ps[3]);
        lpart += (ssv[0]+ssv[1]) + (ssv[2]+ssv[3]);
        // pack P (bf16) to per-wave LDS, k-group-major
        #pragma unroll
        for (int kb=0; kb<4; ++kb) {
            uint2 w;
            w.x = cvtpk_bf16(ps[kb][0], ps[kb][1]);
            w.y = cvtpk_bf16(ps[kb][2], ps[kb][3]);
            *reinterpret_cast<uint2*>(&plds[wid][2*kb + (kg>>1)][rA][(kg&1)<<2]) = w;
        }
        short8 aP0 = *reinterpret_cast<const short8*>(&plds[wid][kg][rA][0]);
        short8 aP1 = *reinterpret_cast<const short8*>(&plds[wid][4+kg][rA][0]);
        #pragma unroll
        for (int dt=0; dt<4; ++dt) {
            const int vo = (dt*16 + rA) * 128;
            short8 bV0 = *reinterpret_cast<const short8*>(Vb + vo + ((kg ^ swz) << 4));
            short8 bV1 = *reinterpret_cast<const short8*>(Vb + vo + (((4+kg) ^ swz) << 4));
            O[dt] = MFMA16(aP0, bV0, O[dt]);
            O[dt] = MFMA16(aP1, bV1, O[dt]);
        }
        __syncthreads();
    }

    float lrow_ = lpart;
    lrow_ += __shfl_xor(lrow_, 16);
    lrow_ += __shfl_xor(lrow_, 32);
    float lq[4];
    #pragma unroll
    for (int j=0;j<4;++j) lq[j] = 1.0f / __shfl(lrow_, (kg<<2)+j);
    const int b = bh >> 4, h = bh & 15;
    #pragma unroll
    for (int dt=0; dt<4; ++dt){
        #pragma unroll
        for (int j=0;j<4;++j){
            int t = qrow0 + (kg<<2) + j;
            int col = h*HD + dt*16 + rA;
            merged[((size_t)(b*TSEQ + t))*EMB + col] = __float2bfloat16(O[dt][j]*lq[j]);
        }
    }
}

// ---------------- residual + layer norm (templated input dtypes) ----------------
// ABF: a is bf16; RBF: res is bf16.
template<int ABF, int RBF>
__global__ __launch_bounds__(256)
void ln_res(const void* __restrict__ a_, const void* __restrict__ res_,
            const float* __restrict__ gain, const float* __restrict__ bias,
            float* __restrict__ outf, __hip_bfloat16* __restrict__ outb)
{
    const int row = blockIdx.x;
    const int tid = threadIdx.x;
    const int lane = tid & 63, wid = tid >> 6;
    const size_t base = (size_t)row * EMB;
    f32x4 va, vr;
    if constexpr (ABF) va = ld4bf((const __hip_bfloat16*)a_ + base + tid*4);
    else               va = *reinterpret_cast<const f32x4*>((const float*)a_ + base + tid*4);
    if constexpr (RBF) vr = ld4bf((const __hip_bfloat16*)res_ + base + tid*4);
    else               vr = *reinterpret_cast<const f32x4*>((const float*)res_ + base + tid*4);
    f32x4 v = va + vr;
    float s = v[0]+v[1]+v[2]+v[3];
    #pragma unroll
    for (int off=1; off<64; off<<=1) s += __shfl_xor(s, off);
    __shared__ float red1[4], red2[4];
    if (lane==0) red1[wid] = s;
    __syncthreads();
    float mean = (red1[0]+red1[1]+red1[2]+red1[3]) * (1.0f/EMB);
    f32x4 d;
    #pragma unroll
    for (int j=0;j<4;++j) d[j] = v[j] - mean;
    float qs = d[0]*d[0]+d[1]*d[1]+d[2]*d[2]+d[3]*d[3];
    #pragma unroll
    for (int off=1; off<64; off<<=1) qs += __shfl_xor(qs, off);
    if (lane==0) red2[wid] = qs;
    __syncthreads();
    float var = (red2[0]+red2[1]+red2[2]+red2[3]) * (1.0f/EMB);
    float r = 1.0f/(sqrtf(var)+LN_EPS);
    f32x4 g = *reinterpret_cast<const f32x4*>(gain + tid*4);
    f32x4 bb = *reinterpret_cast<const f32x4*>(bias + tid*4);
    f32x4 o;
    #pragma unroll
    for (int j=0;j<4;++j) o[j] = g[j]*(d[j]*r) + bb[j];
    if (outf)
        *reinterpret_cast<f32x4*>(outf + base + tid*4) = o;
    if (outb) {
        uint2 ob;
        ob.x = cvtpk_bf16(o[0], o[1]);
        ob.y = cvtpk_bf16(o[2], o[3]);
        *reinterpret_cast<uint2*>(reinterpret_cast<unsigned short*>(outb) + base + tid*4) = ob;
    }
}

// ---------------- launch ----------------
extern "C" void kernel_launch(void* const* d_in, const int* in_sizes, int n_in,
                              void* d_out, int out_size, void* d_ws, size_t ws_size,
                              hipStream_t stream) {
    const float* x   = (const float*)d_in[0];
    const float* Wq  = (const float*)d_in[1];
    const float* Wk  = (const float*)d_in[2];
    const float* Wv  = (const float*)d_in[3];
    const float* Wo  = (const float*)d_in[4];
    const float* W1  = (const float*)d_in[5];
    const float* b1  = (const float*)d_in[6];
    const float* W2  = (const float*)d_in[7];
    const float* b2  = (const float*)d_in[8];
    const float* gain1 = (const float*)d_in[9];
    const float* bias1 = (const float*)d_in[10];
    const float* gain2 = (const float*)d_in[11];
    const float* bias2 = (const float*)d_in[12];

    char* ws = (char*)d_ws;
    __hip_bfloat16* Wqkv_t   = (__hip_bfloat16*)(ws + 0);          // 3072x1024 (+Wo_t right after)
    __hip_bfloat16* Wo_t     = (__hip_bfloat16*)(ws + 6291456);    // 1024x1024
    __hip_bfloat16* W1_t     = (__hip_bfloat16*)(ws + 8388608);    // 4096x1024
    __hip_bfloat16* W2_t     = (__hip_bfloat16*)(ws + 16777216);   // 1024x4096
    __hip_bfloat16* xb       = (__hip_bfloat16*)(ws + 25165824);   // 8192x1024
    __hip_bfloat16* qb       = (__hip_bfloat16*)(ws + 41943040);   // 64x2048x64
    __hip_bfloat16* kbuf     = (__hip_bfloat16*)(ws + 58720256);
    __hip_bfloat16* vtb      = (__hip_bfloat16*)(ws + 75497472);   // 64x64x2048
    __hip_bfloat16* h1       = (__hip_bfloat16*)(ws + 25165824);   // reuse xb..vtb, 8192x4096
    __hip_bfloat16* mergedb  = (__hip_bfloat16*)(ws + 92274688);   // 8192x1024
    __hip_bfloat16* ffb      = (__hip_bfloat16*)(ws + 92274688);   // reuse mergedb
    __hip_bfloat16* attendedb= (__hip_bfloat16*)(ws + 109051904);  // 8192x1024
    __hip_bfloat16* x1b      = (__hip_bfloat16*)(ws + 125829120);  // 8192x1024
    float*          outf     = (float*)d_out;

    dim3 tb(32,8);
    transpose_cvt4<<<dim3(32,32,4), tb, 0, stream>>>(Wq, Wk, Wv, Wo, Wqkv_t);
    transpose_cvt<<<dim3(128,32), tb, 0, stream>>>(W1, W1_t, 1024, 4096);
    transpose_cvt<<<dim3(32,128), tb, 0, stream>>>(W2, W2_t, 4096, 1024);
    cvt_bf16<<<(MROWS*EMB/4 + 255)/256, 256, 0, stream>>>(x, xb, MROWS*EMB/4);

    // QKV projection (fused, 256^2; Q pre-scaled by 1/8 in epilogue)
    gemm256<0><<<dim3(MROWS/256, 3072/256), 512, 0, stream>>>(
        xb, Wqkv_t, MROWS, 3072, EMB, nullptr, nullptr, qb, kbuf, vtb);
    // attention
    attn_fwd<<<dim3(2048), 256, 0, stream>>>(qb, kbuf, vtb, mergedb);
    // output projection (128^2) -> bf16
    gemm_bt<1><<<dim3(MROWS/128, EMB/128), 256, 0, stream>>>(
        mergedb, Wo_t, MROWS, EMB, EMB, attendedb, nullptr);
    // residual + LN1 -> x1 (bf16)
    ln_res<1,0><<<MROWS, 256, 0, stream>>>(attendedb, x, gain1, bias1, nullptr, x1b);
    // FF1: relu(x1 @ W1 + b1) -> bf16 (256^2)
    gemm256<2><<<dim3(MROWS/256, DIM_FF/256), 512, 0, stream>>>(
        x1b, W1_t, MROWS, DIM_FF, EMB, h1, b1, nullptr, nullptr, nullptr);
    // FF2: h1 @ W2 + b2 -> bf16 (128^2)
    gemm_bt<3><<<dim3(MROWS/128, EMB/128), 256, 0, stream>>>(
        h1, W2_t, MROWS, EMB, DIM_FF, ffb, b2);
    // residual + LN2 -> out (f32)
    ln_res<1,1><<<MROWS, 256, 0, stream>>>(ffb, x1b, gain2, bias2, outf, nullptr);
}

// Round 6
// 426.237 us; speedup vs baseline: 1.1442x; 1.0383x over previous
//
#include <hip/hip_runtime.h>
#include <hip/hip_bf16.h>
#include <math.h>

#define EMB 1024
#define DIM_FF 4096
#define HEADS 16
#define HD 64
#define TSEQ 2048
#define BATCH 4
#define MROWS (BATCH*TSEQ)
#define LN_EPS 1e-5f
#define QSCALE 0.18033688011f  /* 0.125 * log2(e): softmax in exp2 domain */

typedef __attribute__((ext_vector_type(8))) short short8;
typedef __attribute__((ext_vector_type(4))) float f32x4;
typedef __attribute__((ext_vector_type(16))) float f32x16;

#define MFMA16(a,b,c) __builtin_amdgcn_mfma_f32_16x16x32_bf16((a),(b),(c),0,0,0)
#define MFMA32(a,b,c) __builtin_amdgcn_mfma_f32_32x32x16_bf16((a),(b),(c),0,0,0)

#define GLOBAL_AS(p) ((const __attribute__((address_space(1))) void*)(p))
#define LDS_AS(p)    ((__attribute__((address_space(3))) void*)(p))

__device__ __forceinline__ unsigned cvtpk_bf16(float lo, float hi){
    unsigned r;
    asm("v_cvt_pk_bf16_f32 %0, %1, %2" : "=v"(r) : "v"(lo), "v"(hi));
    return r;
}
__device__ __forceinline__ f32x4 ld4bf(const __hip_bfloat16* p){
    ushort4 u = *reinterpret_cast<const ushort4*>(p);
    union{unsigned i; float f;} c0,c1,c2,c3;
    c0.i=(unsigned)u.x<<16; c1.i=(unsigned)u.y<<16; c2.i=(unsigned)u.z<<16; c3.i=(unsigned)u.w<<16;
    f32x4 r; r[0]=c0.f; r[1]=c1.f; r[2]=c2.f; r[3]=c3.f;
    return r;
}

// ---------------- convert fp32 -> bf16 (row-major) ----------------
__global__ __launch_bounds__(256)
void cvt_bf16(const float* __restrict__ in, __hip_bfloat16* __restrict__ out, int n4){
    int i = blockIdx.x*256 + threadIdx.x;
    if (i >= n4) return;
    f32x4 v = reinterpret_cast<const f32x4*>(in)[i];
    uint2 o;
    o.x = cvtpk_bf16(v[0], v[1]);
    o.y = cvtpk_bf16(v[2], v[3]);
    *reinterpret_cast<uint2*>(reinterpret_cast<unsigned short*>(out) + (size_t)i*4) = o;
}

// ---------------- fused transpose of the four 1024x1024 weights ----------------
__global__ __launch_bounds__(256)
void transpose_cvt4(const float* __restrict__ s0, const float* __restrict__ s1,
                    const float* __restrict__ s2, const float* __restrict__ s3,
                    __hip_bfloat16* __restrict__ out){
    const float* in = blockIdx.z==0 ? s0 : blockIdx.z==1 ? s1 : blockIdx.z==2 ? s2 : s3;
    __hip_bfloat16* dst = out + (size_t)blockIdx.z*1024*1024;
    __shared__ __hip_bfloat16 tile[32][33];
    int bx = blockIdx.x*32, by = blockIdx.y*32;
    int x = bx + threadIdx.x;
    #pragma unroll
    for (int i = threadIdx.y; i < 32; i += 8)
        tile[i][threadIdx.x] = __float2bfloat16(in[(size_t)(by+i)*1024 + x]);
    __syncthreads();
    int xo = by + threadIdx.x;
    #pragma unroll
    for (int i = threadIdx.y; i < 32; i += 8)
        dst[(size_t)(bx+i)*1024 + xo] = tile[threadIdx.x][i];
}

// ---------------- transpose + convert: in (R x C) fp32 -> out (C x R) bf16 ----------------
__global__ __launch_bounds__(256)
void transpose_cvt(const float* __restrict__ in, __hip_bfloat16* __restrict__ out, int R, int C){
    __shared__ __hip_bfloat16 tile[32][33];
    int bx = blockIdx.x*32, by = blockIdx.y*32;
    int x = bx + threadIdx.x;
    #pragma unroll
    for (int i = threadIdx.y; i < 32; i += 8)
        tile[i][threadIdx.x] = __float2bfloat16(in[(size_t)(by+i)*C + x]);
    __syncthreads();
    int xo = by + threadIdx.x;
    #pragma unroll
    for (int i = threadIdx.y; i < 32; i += 8)
        out[(size_t)(bx+i)*R + xo] = tile[threadIdx.x][i];
}

// ---------------- GEMM 128x128 (m97 structure) ----------------
// EPI: 1 = bf16 out, 3 = +bias -> bf16
template<int EPI>
__global__ __launch_bounds__(256, 2)
void gemm_bt(const __hip_bfloat16* __restrict__ A,
             const __hip_bfloat16* __restrict__ Bt,
             int M, int N, int K,
             __hip_bfloat16* __restrict__ Cb,
             const float* __restrict__ bias)
{
    __shared__ __align__(16) __hip_bfloat16 As[128*32];
    __shared__ __align__(16) __hip_bfloat16 Bs[128*32];
    const int tid = threadIdx.x;
    const int lane = tid & 63;
    const int wid = tid >> 6;
    const int wm = wid >> 1, wn = wid & 1;
    const int row0 = blockIdx.x * 128;
    const int col0 = blockIdx.y * 128;
    const int rA = lane & 15, kg = lane >> 4;

    const int lrow = lane >> 2;
    const int lcol = (lane & 3) << 3;

    f32x4 acc[4][4] = {};

    for (int kt = 0; kt < K; kt += 32) {
        __syncthreads();
        #pragma unroll
        for (int half = 0; half < 2; ++half) {
            const int rbase = (wid << 5) + (half << 4);
            const int r = rbase + lrow;
            __builtin_amdgcn_global_load_lds(
                GLOBAL_AS(A + (size_t)(row0 + r)*K + kt + lcol),
                LDS_AS(&As[rbase*32]), 16, 0, 0);
            __builtin_amdgcn_global_load_lds(
                GLOBAL_AS(Bt + (size_t)(col0 + r)*K + kt + lcol),
                LDS_AS(&Bs[rbase*32]), 16, 0, 0);
        }
        __syncthreads();
        short8 af[4], bfr[4];
        #pragma unroll
        for (int mi = 0; mi < 4; ++mi)
            af[mi] = *reinterpret_cast<const short8*>(&As[(wm*64 + mi*16 + rA)*32 + (kg<<3)]);
        #pragma unroll
        for (int ni = 0; ni < 4; ++ni)
            bfr[ni] = *reinterpret_cast<const short8*>(&Bs[(wn*64 + ni*16 + rA)*32 + (kg<<3)]);
        #pragma unroll
        for (int mi = 0; mi < 4; ++mi)
            #pragma unroll
            for (int ni = 0; ni < 4; ++ni)
                acc[mi][ni] = MFMA16(af[mi], bfr[ni], acc[mi][ni]);
    }

    #pragma unroll
    for (int mi=0; mi<4; ++mi) {
        #pragma unroll
        for (int ni=0; ni<4; ++ni) {
            #pragma unroll
            for (int j=0;j<4;++j){
                float v = acc[mi][ni][j];
                int grow = row0 + wm*64 + mi*16 + (kg<<2) + j;
                int gcol = col0 + wn*64 + ni*16 + rA;
                if constexpr (EPI==3) v += bias[gcol];
                Cb[(size_t)grow*N + gcol] = __float2bfloat16(v);
            }
        }
    }
}

// ---------------- GEMM 256x256, BK=64, 8 waves, 4-phase/K-tile, counted vmcnt ----------------
// EPI: 0 = QKV scatter (Q pre-scaled by QSCALE), 2 = +bias,relu -> bf16
#define GPHASE(P, STAGE_EXPR, WAIT_EXPR) do { \
    short8 af[2][2]; \
    _Pragma("unroll") \
    for (int i_=0;i_<2;++i_){ \
      _Pragma("unroll") \
      for (int kk_=0;kk_<2;++kk_) \
        af[i_][kk_] = *reinterpret_cast<const short8*>(pA + ((2*(P)+i_)*16+rA)*128 + (((kk_<<2)+kg)^swz)*16); \
    } \
    STAGE_EXPR; WAIT_EXPR; \
    __builtin_amdgcn_s_barrier(); \
    __builtin_amdgcn_s_setprio(1); \
    _Pragma("unroll") \
    for (int i_=0;i_<2;++i_){ \
      _Pragma("unroll") \
      for (int ni_=0;ni_<4;++ni_){ \
        acc[2*(P)+i_][ni_] = MFMA16(af[i_][0], bfr[ni_][0], acc[2*(P)+i_][ni_]); \
        acc[2*(P)+i_][ni_] = MFMA16(af[i_][1], bfr[ni_][1], acc[2*(P)+i_][ni_]); \
      } \
    } \
    __builtin_amdgcn_s_setprio(0); \
    __builtin_amdgcn_s_barrier(); \
} while(0)

template<int EPI>
__global__ __launch_bounds__(512, 2)
void gemm256(const __hip_bfloat16* __restrict__ A,
             const __hip_bfloat16* __restrict__ Bt,
             int M, int N, int K,
             __hip_bfloat16* __restrict__ Cb,
             const float* __restrict__ bias,
             __hip_bfloat16* __restrict__ qo,
             __hip_bfloat16* __restrict__ ko,
             __hip_bfloat16* __restrict__ vto)
{
    __shared__ __align__(16) __hip_bfloat16 Al[2][16384];
    __shared__ __align__(16) __hip_bfloat16 Bl[2][16384];
    const int tid = threadIdx.x;
    const int lane = tid & 63;
    const int wid = tid >> 6;
    const int wm = wid >> 2, wn = wid & 3;
    const int row0 = blockIdx.x * 256;
    const int col0 = blockIdx.y * 256;
    const int rA = lane & 15, kg = lane >> 4, swz = rA & 7;
    const int NT = K >> 6;

    const int lr = lane >> 3;
    const int lg = (lane & 7) ^ lr;
    const __hip_bfloat16* sA = A  + (size_t)(row0 + wid*8 + lr)*K + lg*8;
    const __hip_bfloat16* sB = Bt + (size_t)(col0 + wid*8 + lr)*K + lg*8;
    char* dA = (char*)&Al[0][0] + wid*8*128;
    char* dB = (char*)&Bl[0][0] + wid*8*128;

    auto stage = [&](const __hip_bfloat16* s, char* d, int buf, int half, int kt){
        #pragma unroll
        for (int rr = 0; rr < 2; ++rr)
            __builtin_amdgcn_global_load_lds(
                GLOBAL_AS(s + (size_t)(half*128 + rr*64)*K + kt),
                LDS_AS(d + buf*32768 + (half*128 + rr*64)*128), 16, 0, 0);
    };

    f32x4 acc[8][4] = {};

    stage(sA, dA, 0, 0, 0); stage(sA, dA, 0, 1, 0);
    stage(sB, dB, 0, 0, 0); stage(sB, dB, 0, 1, 0);
    stage(sB, dB, 1, 0, 64); stage(sB, dB, 1, 1, 64);
    asm volatile("s_waitcnt vmcnt(4)" ::: "memory");
    __builtin_amdgcn_sched_barrier(0);
    __builtin_amdgcn_s_barrier();

    const char* cA = (const char*)&Al[0][0] + wm*128*128;
    const char* cB = (const char*)&Bl[0][0] + wn*64*128;

    for (int t = 0; t < NT; ++t) {
        const int buf = t & 1;
        const char* pA = cA + buf*32768;
        const char* pB = cB + buf*32768;
        short8 bfr[4][2];
        #pragma unroll
        for (int ni = 0; ni < 4; ++ni)
            #pragma unroll
            for (int kk = 0; kk < 2; ++kk)
                bfr[ni][kk] = *reinterpret_cast<const short8*>(pB + (ni*16+rA)*128 + (((kk<<2)+kg)^swz)*16);

        GPHASE(0, if (t+1 < NT) stage(sA, dA, buf^1, 0, (t+1)*64), );
        GPHASE(1, if (t+1 < NT) stage(sA, dA, buf^1, 1, (t+1)*64), );
        GPHASE(2, if (t+2 < NT) stage(sB, dB, buf,   0, (t+2)*64), );
        GPHASE(3, if (t+2 < NT) stage(sB, dB, buf,   1, (t+2)*64),
            if (t+2 < NT) { asm volatile("s_waitcnt vmcnt(4)" ::: "memory"); }
            else          { asm volatile("s_waitcnt vmcnt(0)" ::: "memory"); }
            __builtin_amdgcn_sched_barrier(0) );
    }

    #pragma unroll
    for (int mi=0; mi<8; ++mi) {
        #pragma unroll
        for (int ni=0; ni<4; ++ni) {
            #pragma unroll
            for (int j=0;j<4;++j){
                float v = acc[mi][ni][j];
                int grow = row0 + wm*128 + mi*16 + (kg<<2) + j;
                int gcol = col0 + wn*64 + ni*16 + rA;
                if constexpr (EPI==0) {
                    int b = grow >> 11, t = grow & 2047;
                    int which = gcol >> 10, hdx = gcol & 1023;
                    int h = hdx >> 6, d = hdx & 63;
                    int bh = b*HEADS + h;
                    if (which==0)      qo[((size_t)bh*TSEQ + t)*HD + d] = __float2bfloat16(v*QSCALE);
                    else if (which==1) ko[((size_t)bh*TSEQ + t)*HD + d] = __float2bfloat16(v);
                    else               vto[((size_t)bh*HD + d)*TSEQ + t] = __float2bfloat16(v);
                } else {
                    v += bias[gcol]; v = v > 0.0f ? v : 0.0f;
                    Cb[(size_t)grow*N + gcol] = __float2bfloat16(v);
                }
            }
        }
    }
}

// ---------------- flash attention, 32x32 MFMA, 32 q-rows/wave ----------------
// Swapped QK^T: S^T = mfma32(K_rows, Q) -> lane owns q-column (lane&31); scores
// in exp2 domain (Q pre-scaled). P->PV A-frag built in-register via cvt_pk +
// shfl_xor(32) + cndmask. K/V staged to LDS (dbuf, pre-swizzled source).
__global__ __launch_bounds__(256, 4)
void attn_fwd(const __hip_bfloat16* __restrict__ q,
              const __hip_bfloat16* __restrict__ k,
              const __hip_bfloat16* __restrict__ vt,
              __hip_bfloat16* __restrict__ merged)
{
    // bijective XCD swizzle: 1024 blocks = 8 x 128
    const int wg = (blockIdx.x & 7) * 128 + (blockIdx.x >> 3);
    const int bh = wg >> 4;          // 0..63
    const int qt = wg & 15;          // 0..15
    const int wid = threadIdx.x >> 6, lane = threadIdx.x & 63;
    const int l31 = lane & 31;       // q-col for QK/PV-D; k-row for K A-frag; d for V B-frag
    const int hi  = lane >> 5;
    const int swz = lane & 7;
    const int qrow0 = qt*128 + wid*32;
    const __hip_bfloat16* Qh = q  + (size_t)bh*TSEQ*HD;
    const __hip_bfloat16* Kh = k  + (size_t)bh*TSEQ*HD;
    const __hip_bfloat16* Vh = vt + (size_t)bh*HD*TSEQ;

    __shared__ __align__(16) __hip_bfloat16 Kl[2][64*64];
    __shared__ __align__(16) __hip_bfloat16 Vl[2][64*64];

    // Q fragments (B-operand of 32x32x16): col=l31, k=hi*8+e within 16-chunk c
    short8 qv[4];
    #pragma unroll
    for (int c=0;c<4;++c)
        qv[c] = *reinterpret_cast<const short8*>(Qh + (size_t)(qrow0+l31)*HD + c*16 + hi*8);

    // staging: wave wid stages rows [wid*16, wid*16+16) of the 64-row K/V tiles
    const int lrow = lane >> 3;
    const int lslot = ((lane & 7) ^ lrow) << 3;
    const __hip_bfloat16* sK0 = Kh + (size_t)(wid*16 + lrow)*HD + lslot;
    const __hip_bfloat16* sV0 = Vh + (size_t)(wid*16 + lrow)*TSEQ + lslot;
    const int dOff = wid*16*64;

    f32x16 O0 = {}, O1 = {};
    float m = -1e30f, lpart = 0.f;

    {
        __builtin_amdgcn_global_load_lds(GLOBAL_AS(sK0),          LDS_AS(&Kl[0][dOff]),        16, 0, 0);
        __builtin_amdgcn_global_load_lds(GLOBAL_AS(sK0 + 8*HD),   LDS_AS(&Kl[0][dOff + 8*64]), 16, 0, 0);
        __builtin_amdgcn_global_load_lds(GLOBAL_AS(sV0),          LDS_AS(&Vl[0][dOff]),        16, 0, 0);
        __builtin_amdgcn_global_load_lds(GLOBAL_AS(sV0 + 8*TSEQ), LDS_AS(&Vl[0][dOff + 8*64]), 16, 0, 0);
    }
    __syncthreads();

    for (int t = 0; t < TSEQ/64; ++t) {
        const int b = t & 1;
        if (t < TSEQ/64 - 1) {
            const int kt = (t+1)*64;
            __builtin_amdgcn_global_load_lds(GLOBAL_AS(sK0 + (size_t)kt*HD),     LDS_AS(&Kl[b^1][dOff]),        16, 0, 0);
            __builtin_amdgcn_global_load_lds(GLOBAL_AS(sK0 + (size_t)(kt+8)*HD), LDS_AS(&Kl[b^1][dOff + 8*64]), 16, 0, 0);
            __builtin_amdgcn_global_load_lds(GLOBAL_AS(sV0 + kt),                LDS_AS(&Vl[b^1][dOff]),        16, 0, 0);
            __builtin_amdgcn_global_load_lds(GLOBAL_AS(sV0 + 8*TSEQ + kt),       LDS_AS(&Vl[b^1][dOff + 8*64]), 16, 0, 0);
        }
        const char* Kb = (const char*)&Kl[b][0];
        const char* Vb = (const char*)&Vl[b][0];

        // QK^T: st0 = k 0..31, st1 = k 32..63 (S^T: lane holds q-col l31)
        f32x16 st0 = {}, st1 = {};
        #pragma unroll
        for (int c=0;c<4;++c) {
            short8 ka0 = *reinterpret_cast<const short8*>(Kb + l31*128        + (((2*c+hi)^swz)<<4));
            short8 ka1 = *reinterpret_cast<const short8*>(Kb + (32+l31)*128   + (((2*c+hi)^swz)<<4));
            st0 = MFMA32(ka0, qv[c], st0);
            st1 = MFMA32(ka1, qv[c], st1);
        }

        // row max over this lane's 32 scores + partner exchange
        float mr[16];
        #pragma unroll
        for (int r=0;r<16;++r) mr[r] = fmaxf(st0[r], st1[r]);
        #pragma unroll
        for (int s=8; s>0; s>>=1)
            #pragma unroll
            for (int i=0;i<8;++i) if (i<s) mr[i] = fmaxf(mr[i], mr[i+s]);
        float mx = mr[0];
        mx = fmaxf(mx, __shfl_xor(mx, 32));

        // defer-max (log2 units, THR=8)
        if (!__all(mx - m <= 8.0f)) {
            float mn = fmaxf(m, mx);
            float al = __builtin_amdgcn_exp2f(m - mn);
            lpart *= al;
            #pragma unroll
            for (int r=0;r<16;++r) {
                float alr = __shfl(al, (r&3) + 8*(r>>2) + 4*hi);
                O0[r] *= alr; O1[r] *= alr;
            }
            m = mn;
        }
        // p = exp2(s - m)
        #pragma unroll
        for (int r=0;r<16;++r) {
            st0[r] = __builtin_amdgcn_exp2f(st0[r] - m);
            st1[r] = __builtin_amdgcn_exp2f(st1[r] - m);
        }
        {
            f32x16 ss = st0 + st1;
            float s8 = (((ss[0]+ss[1])+(ss[2]+ss[3]))+((ss[4]+ss[5])+(ss[6]+ss[7])))
                     + (((ss[8]+ss[9])+(ss[10]+ss[11]))+((ss[12]+ss[13])+(ss[14]+ss[15])));
            lpart += s8;
        }
        // pack pairs: pk[t][j] = bf16x2(p[2j], p[2j+1])
        unsigned pk0[8], pk1[8];
        #pragma unroll
        for (int j=0;j<8;++j) {
            pk0[j] = cvtpk_bf16(st0[2*j], st0[2*j+1]);
            pk1[j] = cvtpk_bf16(st1[2*j], st1[2*j+1]);
        }
        // PV: 4 k-chunks of 16; A-frag from pk/sw via partner swap + select
        #pragma unroll
        for (int kc=0; kc<4; ++kc) {
            const unsigned* pkt = (kc>>1) ? pk1 : pk0;
            const int j0 = 4*(kc&1);
            unsigned swA = (unsigned)__shfl_xor((int)pkt[j0+0], 32);
            unsigned swB = (unsigned)__shfl_xor((int)pkt[j0+1], 32);
            unsigned swC = (unsigned)__shfl_xor((int)pkt[j0+2], 32);
            unsigned swD = (unsigned)__shfl_xor((int)pkt[j0+3], 32);
            union { unsigned u[4]; short8 s; } pa;
            pa.u[0] = hi ? swC : pkt[j0+0];
            pa.u[1] = hi ? swD : pkt[j0+1];
            pa.u[2] = hi ? pkt[j0+2] : swA;
            pa.u[3] = hi ? pkt[j0+3] : swB;
            short8 vf0 = *reinterpret_cast<const short8*>(Vb + l31*128      + (((2*kc+hi)^swz)<<4));
            short8 vf1 = *reinterpret_cast<const short8*>(Vb + (32+l31)*128 + (((2*kc+hi)^swz)<<4));
            O0 = MFMA32(pa.s, vf0, O0);
            O1 = MFMA32(pa.s, vf1, O1);
        }
        __syncthreads();
    }

    lpart += __shfl_xor(lpart, 32);
    float linv = 1.0f / lpart;
    const int b = bh >> 4, h = bh & 15;
    #pragma unroll
    for (int r=0;r<16;++r){
        int qp = (r&3) + 8*(r>>2) + 4*hi;
        float lr = __shfl(linv, qp);
        size_t base = ((size_t)(b*TSEQ + qrow0 + qp))*EMB + h*HD;
        merged[base + l31]      = __float2bfloat16(O0[r]*lr);
        merged[base + 32 + l31] = __float2bfloat16(O1[r]*lr);
    }
}

// ---------------- residual + layer norm (templated input dtypes) ----------------
template<int ABF, int RBF>
__global__ __launch_bounds__(256)
void ln_res(const void* __restrict__ a_, const void* __restrict__ res_,
            const float* __restrict__ gain, const float* __restrict__ bias,
            float* __restrict__ outf, __hip_bfloat16* __restrict__ outb)
{
    const int row = blockIdx.x;
    const int tid = threadIdx.x;
    const int lane = tid & 63, wid = tid >> 6;
    const size_t base = (size_t)row * EMB;
    f32x4 va, vr;
    if constexpr (ABF) va = ld4bf((const __hip_bfloat16*)a_ + base + tid*4);
    else               va = *reinterpret_cast<const f32x4*>((const float*)a_ + base + tid*4);
    if constexpr (RBF) vr = ld4bf((const __hip_bfloat16*)res_ + base + tid*4);
    else               vr = *reinterpret_cast<const f32x4*>((const float*)res_ + base + tid*4);
    f32x4 v = va + vr;
    float s = v[0]+v[1]+v[2]+v[3];
    #pragma unroll
    for (int off=1; off<64; off<<=1) s += __shfl_xor(s, off);
    __shared__ float red1[4], red2[4];
    if (lane==0) red1[wid] = s;
    __syncthreads();
    float mean = (red1[0]+red1[1]+red1[2]+red1[3]) * (1.0f/EMB);
    f32x4 d;
    #pragma unroll
    for (int j=0;j<4;++j) d[j] = v[j] - mean;
    float qs = d[0]*d[0]+d[1]*d[1]+d[2]*d[2]+d[3]*d[3];
    #pragma unroll
    for (int off=1; off<64; off<<=1) qs += __shfl_xor(qs, off);
    if (lane==0) red2[wid] = qs;
    __syncthreads();
    float var = (red2[0]+red2[1]+red2[2]+red2[3]) * (1.0f/EMB);
    float r = 1.0f/(sqrtf(var)+LN_EPS);
    f32x4 g = *reinterpret_cast<const f32x4*>(gain + tid*4);
    f32x4 bb = *reinterpret_cast<const f32x4*>(bias + tid*4);
    f32x4 o;
    #pragma unroll
    for (int j=0;j<4;++j) o[j] = g[j]*(d[j]*r) + bb[j];
    if (outf)
        *reinterpret_cast<f32x4*>(outf + base + tid*4) = o;
    if (outb) {
        uint2 ob;
        ob.x = cvtpk_bf16(o[0], o[1]);
        ob.y = cvtpk_bf16(o[2], o[3]);
        *reinterpret_cast<uint2*>(reinterpret_cast<unsigned short*>(outb) + base + tid*4) = ob;
    }
}

// ---------------- launch ----------------
extern "C" void kernel_launch(void* const* d_in, const int* in_sizes, int n_in,
                              void* d_out, int out_size, void* d_ws, size_t ws_size,
                              hipStream_t stream) {
    const float* x   = (const float*)d_in[0];
    const float* Wq  = (const float*)d_in[1];
    const float* Wk  = (const float*)d_in[2];
    const float* Wv  = (const float*)d_in[3];
    const float* Wo  = (const float*)d_in[4];
    const float* W1  = (const float*)d_in[5];
    const float* b1  = (const float*)d_in[6];
    const float* W2  = (const float*)d_in[7];
    const float* b2  = (const float*)d_in[8];
    const float* gain1 = (const float*)d_in[9];
    const float* bias1 = (const float*)d_in[10];
    const float* gain2 = (const float*)d_in[11];
    const float* bias2 = (const float*)d_in[12];

    char* ws = (char*)d_ws;
    __hip_bfloat16* Wqkv_t   = (__hip_bfloat16*)(ws + 0);          // 3072x1024 (+Wo_t right after)
    __hip_bfloat16* Wo_t     = (__hip_bfloat16*)(ws + 6291456);    // 1024x1024
    __hip_bfloat16* W1_t     = (__hip_bfloat16*)(ws + 8388608);    // 4096x1024
    __hip_bfloat16* W2_t     = (__hip_bfloat16*)(ws + 16777216);   // 1024x4096
    __hip_bfloat16* xb       = (__hip_bfloat16*)(ws + 25165824);   // 8192x1024
    __hip_bfloat16* qb       = (__hip_bfloat16*)(ws + 41943040);   // 64x2048x64
    __hip_bfloat16* kbuf     = (__hip_bfloat16*)(ws + 58720256);
    __hip_bfloat16* vtb      = (__hip_bfloat16*)(ws + 75497472);   // 64x64x2048
    __hip_bfloat16* h1       = (__hip_bfloat16*)(ws + 25165824);   // reuse xb..vtb, 8192x4096
    __hip_bfloat16* mergedb  = (__hip_bfloat16*)(ws + 92274688);   // 8192x1024
    __hip_bfloat16* ffb      = (__hip_bfloat16*)(ws + 92274688);   // reuse mergedb
    __hip_bfloat16* attendedb= (__hip_bfloat16*)(ws + 109051904);  // 8192x1024
    __hip_bfloat16* x1b      = (__hip_bfloat16*)(ws + 125829120);  // 8192x1024
    float*          outf     = (float*)d_out;

    dim3 tb(32,8);
    transpose_cvt4<<<dim3(32,32,4), tb, 0, stream>>>(Wq, Wk, Wv, Wo, Wqkv_t);
    transpose_cvt<<<dim3(128,32), tb, 0, stream>>>(W1, W1_t, 1024, 4096);
    transpose_cvt<<<dim3(32,128), tb, 0, stream>>>(W2, W2_t, 4096, 1024);
    cvt_bf16<<<(MROWS*EMB/4 + 255)/256, 256, 0, stream>>>(x, xb, MROWS*EMB/4);

    // QKV projection (fused, 256^2; Q pre-scaled by 0.125*log2e in epilogue)
    gemm256<0><<<dim3(MROWS/256, 3072/256), 512, 0, stream>>>(
        xb, Wqkv_t, MROWS, 3072, EMB, nullptr, nullptr, qb, kbuf, vtb);
    // attention (32x32, 1024 blocks x 4 waves)
    attn_fwd<<<dim3(1024), 256, 0, stream>>>(qb, kbuf, vtb, mergedb);
    // output projection (128^2) -> bf16
    gemm_bt<1><<<dim3(MROWS/128, EMB/128), 256, 0, stream>>>(
        mergedb, Wo_t, MROWS, EMB, EMB, attendedb, nullptr);
    // residual + LN1 -> x1 (bf16)
    ln_res<1,0><<<MROWS, 256, 0, stream>>>(attendedb, x, gain1, bias1, nullptr, x1b);
    // FF1: relu(x1 @ W1 + b1) -> bf16 (256^2)
    gemm256<2><<<dim3(MROWS/256, DIM_FF/256), 512, 0, stream>>>(
        x1b, W1_t, MROWS, DIM_FF, EMB, h1, b1, nullptr, nullptr, nullptr);
    // FF2: h1 @ W2 + b2 -> bf16 (128^2)
    gemm_bt<3><<<dim3(MROWS/128, EMB/128), 256, 0, stream>>>(
        h1, W2_t, MROWS, EMB, DIM_FF, ffb, b2);
    // residual + LN2 -> out (f32)
    ln_res<1,1><<<MROWS, 256, 0, stream>>>(ffb, x1b, gain2, bias2, outf, nullptr);
}